// Round 12
// baseline (249.868 us; speedup 1.0000x reference)
//
#include <hip/hip_runtime.h>

// SAGEConv x2 forward. Edges bucket-partitioned by dst (256 nodes/bucket).
// Pipeline (5 dispatches, no host-side memset — graph-capture safe):
//   prep        : zero bhist/done, convert weights to bf16
//   hist_scan   : bucket histogram + (last block) padded prefix scan
//   gemm1_part  : MFMA gemm1 + partition in ONE grid; partition uses an
//                 8 KB ushort perm[] (not a 16 KB payload stage) so the
//                 whole kernel's LDS = 17.4 KB -> 8 blocks/CU
//   agg1_gemm2  : LDS sort + fp8 gather-mean (R0 loop shape, uint2/lane) +
//                 h in LDS + MFMA gemm2 -> hl fp8 / hr bf16 (LDS-staged)
//   agg2_final  : gather-mean over hl fp8 (3.2 MB, per-XCD-L2-resident) + epi
// Lessons encoded: in-block LDS sort beats global-CSR precompute (R10);
// ALL scattered stores go LDS->coalesced uint4 (R8/R9); fp8 tables halve
// gather bytes at unchanged request count (R11); LDS union sizing gates
// occupancy of every block in a fused grid (R12).

constexpr int IN_DIM  = 128;
constexpr int HID     = 64;
constexpr int OUT_DIM = 32;
constexpr float SLOPE = 0.1f;
constexpr int NPB_SHIFT = 8;     // 256 nodes per bucket
constexpr int NBMAX = 512;       // max buckets (N <= 131072)
constexpr int CHUNK = 4096;      // edges per partition block
constexpr int SUBCAP = 4096;     // per-half-bucket edge capacity (avg ~2048)

typedef unsigned int uint32;
typedef unsigned short ushort16;
typedef unsigned char uchar8;
using floatx2 = __attribute__((ext_vector_type(2))) float;

__device__ inline float blo(uint32 u) { return __uint_as_float(u << 16); }
__device__ inline float bhi(uint32 u) { return __uint_as_float(u & 0xffff0000u); }
__device__ inline ushort16 f2b(float f) {
    uint32 u = __float_as_uint(f);
    u += 0x7fffu + ((u >> 16) & 1u);   // round-to-nearest-even
    return (ushort16)(u >> 16);
}
__device__ inline uint32 pack2(float lo, float hi) {
    return (uint32)f2b(lo) | ((uint32)f2b(hi) << 16);
}
__device__ inline float lrelu(float v) { return (v > 0.f) ? v : SLOPE * v; }
__device__ inline uchar8 f2fp8(float f) {                // e4m3, RNE (HW)
    uint32 r = (uint32)__builtin_amdgcn_cvt_pk_fp8_f32(f, f, 0, false);
    return (uchar8)(r & 0xffu);
}
__device__ inline void addp4(float* acc, uint32 w) {     // fp8 x4 decode+add
    floatx2 a = __builtin_amdgcn_cvt_pk_f32_fp8((int)w, false);
    floatx2 b = __builtin_amdgcn_cvt_pk_f32_fp8((int)w, true);
    acc[0] += a[0]; acc[1] += a[1]; acc[2] += b[0]; acc[3] += b[1];
}
__device__ inline void addq8(float* acc, uint2 u) {      // fp8 x8
    addp4(acc + 0, u.x); addp4(acc + 4, u.y);
}

// ---- prep: zero bhist/done + convert weights to bf16 [col][k] layouts ----
__global__ __launch_bounds__(256) void prep_kernel(
    const float* __restrict__ Wl1, const float* __restrict__ Wr1,
    const float* __restrict__ Wl2, const float* __restrict__ Wr2,
    ushort16* __restrict__ Wb1, ushort16* __restrict__ Wb2,
    int* __restrict__ bhist, int* __restrict__ done) {
    const int gid = blockIdx.x * 256 + threadIdx.x;
    if (gid < NBMAX) bhist[gid] = 0;
    if (gid == NBMAX) *done = 0;
    for (int i = gid; i < 128 * 128; i += gridDim.x * 256) {
        int c = i >> 7, k = i & 127;
        Wb1[i] = f2b((c < HID) ? Wl1[k * HID + c] : Wr1[k * HID + (c - HID)]);
    }
    for (int i = gid; i < 64 * 64; i += gridDim.x * 256) {
        int c = i >> 6, k = i & 63;
        Wb2[i] = f2b((c < OUT_DIM) ? Wl2[k * OUT_DIM + c]
                                   : Wr2[k * OUT_DIM + (c - OUT_DIM)]);
    }
}

// ---- bucket histogram + fused scan (last-finishing block) ----
__global__ __launch_bounds__(256) void hist_scan_kernel(
    const int* __restrict__ dst, int* __restrict__ bhist,
    int* __restrict__ pbase, int* __restrict__ bcur,
    int* __restrict__ done, int E, int NB) {
    __shared__ int bh[NBMAX];
    __shared__ int s2[256];
    __shared__ int flag;
    const int tid = threadIdx.x;
    for (int i = tid; i < NBMAX; i += 256) bh[i] = 0;
    __syncthreads();
    for (int e = blockIdx.x * 256 + tid; e < E; e += gridDim.x * 256)
        atomicAdd(&bh[dst[e] >> NPB_SHIFT], 1);
    __syncthreads();
    for (int b = tid; b < NBMAX; b += 256)
        if (bh[b]) atomicAdd(&bhist[b], bh[b]);
    __threadfence();
    if (tid == 0) flag = (atomicAdd(done, 1) == (int)gridDim.x - 1) ? 1 : 0;
    __syncthreads();
    if (!flag) return;
    // last block: exclusive scan of 16-padded bucket sizes (512 bins, 256 thr)
    __threadfence();
    int v0 = atomicAdd(&bhist[2 * tid], 0);       // coherent-point read
    int v1 = atomicAdd(&bhist[2 * tid + 1], 0);
    int p0 = (v0 + 15) & ~15, p1 = (v1 + 15) & ~15;
    s2[tid] = p0 + p1; __syncthreads();
    for (int off = 1; off < 256; off <<= 1) {
        int b = (tid >= off) ? s2[tid - off] : 0;
        __syncthreads();
        s2[tid] += b;
        __syncthreads();
    }
    int base = s2[tid] - (p0 + p1);
    pbase[2 * tid]     = base;      bcur[2 * tid]     = base;
    pbase[2 * tid + 1] = base + p0; bcur[2 * tid + 1] = base + p0;
}

// ---- fused: partition blocks (blockIdx < npart) + MFMA gemm1 blocks ----
// partition: edges -> bucket regions of pairs[] via ushort perm[] (LDS-thin:
// flush re-reads src/dst at e0+perm[i], L2-resident) + binary-search bucket.
// gemm1: x[N,128] @ Wb1 -> xl fp8[N,64], xr bf16[N,64]+b1 (LDS-staged
// coalesced stores). A-tile-only LDS. Whole-kernel LDS = 17.4 KB.
__global__ __launch_bounds__(256) void gemm1_part_kernel(
    const float* __restrict__ x, const ushort16* __restrict__ Wb1,
    const float* __restrict__ b1,
    const int* __restrict__ src, const int* __restrict__ dst,
    int* __restrict__ bcur, uint32* __restrict__ pairs,
    uchar8* __restrict__ xl8, ushort16* __restrict__ xr,
    int N, int E, int NB, int npart) {
    using frag = __attribute__((ext_vector_type(8))) short;
    using f32x4 = __attribute__((ext_vector_type(4))) float;
    constexpr int LDA = IN_DIM + 8;                 // 136 elems = 272 B
    __shared__ union {
        struct {
            int hist[NBMAX], loff[NBMAX], cur[NBMAX], gbase[NBMAX];
            int s[256];
            ushort16 perm[CHUNK];                   // 8 KB (was 16 KB stage)
        } p;                                        // 17.0 KB
        ushort16 Ash[64][LDA];                      // 17.4 KB
        struct { uchar8 xl[64][64]; ushort16 xr[64][64]; } o;  // 12 KB stage
    } sm;
    const int tid = threadIdx.x;
    if (blockIdx.x < npart) {                       // ---- partition path ----
        const int e0  = blockIdx.x * CHUNK;
        const int cnt = min(CHUNK, E - e0);
        for (int i = tid; i < NBMAX; i += 256) sm.p.hist[i] = 0;
        __syncthreads();
        int dreg[16];
#pragma unroll
        for (int k = 0; k < 16; ++k) {
            int i = tid + k * 256;
            if (i < cnt) {
                dreg[k] = dst[e0 + i];
                atomicAdd(&sm.p.hist[dreg[k] >> NPB_SHIFT], 1);
            }
        }
        __syncthreads();
        int a0 = sm.p.hist[2 * tid], a1 = sm.p.hist[2 * tid + 1];
        sm.p.s[tid] = a0 + a1; __syncthreads();
        for (int off = 1; off < 256; off <<= 1) {
            int t = (tid >= off) ? sm.p.s[tid - off] : 0;
            __syncthreads();
            sm.p.s[tid] += t;
            __syncthreads();
        }
        int ex = sm.p.s[tid] - (a0 + a1);
        sm.p.loff[2 * tid] = ex;      sm.p.loff[2 * tid + 1] = ex + a0;
        sm.p.cur[2 * tid]  = ex;      sm.p.cur[2 * tid + 1]  = ex + a0;
        __syncthreads();
#pragma unroll
        for (int k = 0; k < 16; ++k) {              // scatter perm only
            int i = tid + k * 256;
            if (i < cnt) {
                int b = dreg[k] >> NPB_SHIFT;
                int pos = atomicAdd(&sm.p.cur[b], 1);
                sm.p.perm[pos] = (ushort16)i;
            }
        }
        __syncthreads();
        for (int b = tid; b < NB; b += 256) {
            int cb = sm.p.hist[b];
            if (cb) sm.p.gbase[b] = atomicAdd(&bcur[b], cb);
        }
        __syncthreads();
        for (int i = tid; i < cnt; i += 256) {      // flush: re-read via perm
            int pidx = sm.p.perm[i];
            int sv = src[e0 + pidx];                // L2-resident (just read)
            int dv = dst[e0 + pidx];
            int lo = 0, hi = NB - 1;                // invariant: loff[lo] <= i
            while (lo < hi) {
                int mid = (lo + hi + 1) >> 1;
                if (sm.p.loff[mid] <= i) lo = mid; else hi = mid - 1;
            }
            pairs[sm.p.gbase[lo] + (i - sm.p.loff[lo])] =
                (uint32)sv | ((uint32)(dv & 255) << 24);
        }
        return;
    }
    // ---- gemm1 path ----
    const int n0 = (blockIdx.x - npart) * 64;
    {
        const int lc = (tid & 31) * 4;
        for (int row = tid >> 5; row < 64; row += 8) {
            int node = n0 + row;
            float4 xv = (node < N)
                ? *reinterpret_cast<const float4*>(&x[(long)node * IN_DIM + lc])
                : float4{0.f, 0.f, 0.f, 0.f};
            ushort16 pk[4] = {f2b(xv.x), f2b(xv.y), f2b(xv.z), f2b(xv.w)};
            *reinterpret_cast<ushort2*>(&sm.Ash[row][lc])     = ushort2{pk[0], pk[1]};
            *reinterpret_cast<ushort2*>(&sm.Ash[row][lc + 2]) = ushort2{pk[2], pk[3]};
        }
    }
    __syncthreads();
    const int lane = tid & 63;
    const int m0   = (tid >> 6) * 16;
    const int mlo  = lane & 15;
    const int qk   = lane >> 4;
    frag Af[4];
#pragma unroll
    for (int kc = 0; kc < 4; ++kc)
        Af[kc] = *reinterpret_cast<const frag*>(&sm.Ash[m0 + mlo][kc * 32 + qk * 8]);
    __syncthreads();                                // Ash dead -> o reuse
#pragma unroll
    for (int ct = 0; ct < 8; ++ct) {
        f32x4 acc = {0.f, 0.f, 0.f, 0.f};
#pragma unroll
        for (int kc = 0; kc < 4; ++kc) {
            frag Bf = *reinterpret_cast<const frag*>(
                &Wb1[(ct * 16 + mlo) * 128 + kc * 32 + qk * 8]);
            acc = __builtin_amdgcn_mfma_f32_16x16x32_bf16(Af[kc], Bf, acc, 0, 0, 0);
        }
        const int col = ct * 16 + mlo;
#pragma unroll
        for (int r = 0; r < 4; ++r) {
            int row = m0 + qk * 4 + r;
            if (col < HID) sm.o.xl[row][col] = f2fp8(acc[r]);
            else           sm.o.xr[row][col - HID] = f2b(acc[r] + b1[col - HID]);
        }
    }
    __syncthreads();
    // coalesced bulk stores: xl 64x4 uint4, xr 64x8 uint4
    for (int idx = tid; idx < 64 * 4; idx += 256) {
        int row = idx >> 2, ch = idx & 3;
        int node = n0 + row;
        if (node < N)
            reinterpret_cast<uint4*>(xl8)[(long)node * 4 + ch] =
                reinterpret_cast<const uint4*>(&sm.o.xl[0][0])[idx];
    }
    for (int idx = tid; idx < 64 * 8; idx += 256) {
        int row = idx >> 3, ch = idx & 7;
        int node = n0 + row;
        if (node < N)
            reinterpret_cast<uint4*>(xr)[(long)node * 8 + ch] =
                reinterpret_cast<const uint4*>(&sm.o.xr[0][0])[idx];
    }
}

// ---- agg1 + fine-bin + gemm2 fused: block = half-bucket (128 nodes) ----
// Sorts the bucket's pairs in LDS, emits CSR (srcs/rowptr/deg) for agg2,
// computes h = LR(mean-gather(xl fp8) + xr bf16) into an LDS bf16 tile
// (R0 loop shape: 8 lanes/node x uint2, 2 passes, 16/8/tail), then the
// 128x64 @ 64x64 MFMA gemm2 -> hl fp8 / hr bf16 staged in LDS, coalesced.
__global__ __launch_bounds__(512) void agg1_gemm2_kernel(
    const uint32* __restrict__ pairs, const int* __restrict__ bhist,
    const int* __restrict__ pbase,
    const uint2* __restrict__ xlq, const uint4* __restrict__ xrq,
    const ushort16* __restrict__ Wb2, const float* __restrict__ b2,
    uint32* __restrict__ srcs, int* __restrict__ rowptr, int* __restrict__ degA,
    uchar8* __restrict__ hl8, ushort16* __restrict__ hr, int N) {
    using frag = __attribute__((ext_vector_type(8))) short;
    using f32x4 = __attribute__((ext_vector_type(4))) float;
    constexpr int LDH = HID + 8;                    // 72 elems = 144 B
    __shared__ int hist[256], loff[256], cur[128];
    __shared__ int lsrc[SUBCAP];                    // 16 KB (reused as out-stage)
    __shared__ ushort16 hsh[128][LDH];              // 18 KB bf16 h-tile
    const int tid  = threadIdx.x;
    const int bkt  = blockIdx.x >> 1;
    const int half = blockIdx.x & 1;
    const int n0   = bkt << NPB_SHIFT;
    const int base = pbase[bkt];
    const int sz   = bhist[bkt];
    if (tid < 256) hist[tid] = 0;
    __syncthreads();
    for (int i = tid; i < sz; i += 512)
        atomicAdd(&hist[pairs[base + i] >> 24], 1);
    __syncthreads();
    int v = (tid < 256) ? hist[tid] : 0;
    if (tid < 256) loff[tid] = v;
    __syncthreads();
    for (int off = 1; off < 256; off <<= 1) {
        int t = (tid >= off && tid < 256) ? loff[tid - off] : 0;
        __syncthreads();
        if (tid < 256) loff[tid] += t;
        __syncthreads();
    }
    if (tid < 256) loff[tid] -= v;                  // exclusive
    __syncthreads();
    if (half == 0 && tid < 256 && n0 + tid < N) {   // CSR for agg2
        rowptr[n0 + tid] = base + loff[tid];
        degA[n0 + tid]   = hist[tid];
    }
    const int hbase = loff[half << 7];
    const int hcnt  = (half ? sz : loff[128]) - hbase;
    if (tid < 128) cur[tid] = loff[(half << 7) + tid] - hbase;
    __syncthreads();
    for (int i = tid; i < sz; i += 512) {           // scatter my half into lsrc
        uint32 u = pairs[base + i];
        int dl = u >> 24;
        if ((dl >> 7) == half) {
            int pos = atomicAdd(&cur[dl & 127], 1);
            lsrc[pos] = (int)(u & 0xFFFFFFu);
        }
    }
    __syncthreads();
    for (int i = tid; i < hcnt; i += 512)           // coalesced CSR srcs
        srcs[base + hbase + i] = (uint32)lsrc[i];
    // ---- gather: 8 lanes/node x uint2 fp8, 8 nodes/wave, 2 passes ----
    const int lane = tid & 63;
    const int wid  = tid >> 6;
    const int li   = lane & 7;
#pragma unroll
    for (int pass = 0; pass < 2; ++pass) {
        const int nll = pass * 64 + wid * 8 + (lane >> 3);  // row in hsh 0..127
        const int nl  = (half << 7) + nll;
        const int n   = n0 + nl;
        if (n >= N) continue;
        const int lo0 = loff[nl] - hbase;
        const int d   = hist[nl];
        float acc[8] = {};
        int j = 0;
        while (j + 16 <= d) {
            int i0[8], i1[8];
#pragma unroll
            for (int t = 0; t < 8; ++t) i0[t] = lsrc[lo0 + j + t];
#pragma unroll
            for (int t = 0; t < 8; ++t) i1[t] = lsrc[lo0 + j + 8 + t];
            uint2 u0[8], u1[8];
#pragma unroll
            for (int t = 0; t < 8; ++t) u0[t] = xlq[(long)i0[t] * 8 + li];
#pragma unroll
            for (int t = 0; t < 8; ++t) u1[t] = xlq[(long)i1[t] * 8 + li];
#pragma unroll
            for (int t = 0; t < 8; ++t) { addq8(acc, u0[t]); addq8(acc, u1[t]); }
            j += 16;
        }
        if (j + 8 <= d) {
            int i0[8];
#pragma unroll
            for (int t = 0; t < 8; ++t) i0[t] = lsrc[lo0 + j + t];
            uint2 u0[8];
#pragma unroll
            for (int t = 0; t < 8; ++t) u0[t] = xlq[(long)i0[t] * 8 + li];
#pragma unroll
            for (int t = 0; t < 8; ++t) addq8(acc, u0[t]);
            j += 8;
        }
        for (; j < d; ++j) {
            uint2 u = xlq[(long)lsrc[lo0 + j] * 8 + li];
            addq8(acc, u);
        }
        const float dinv = (d > 0) ? (1.f / (float)d) : 1.f;
        uint4 xv = xrq[(long)n * 8 + li];           // 8 bf16 xr values
        float h[8];
        h[0] = fmaf(acc[0], dinv, blo(xv.x)); h[1] = fmaf(acc[1], dinv, bhi(xv.x));
        h[2] = fmaf(acc[2], dinv, blo(xv.y)); h[3] = fmaf(acc[3], dinv, bhi(xv.y));
        h[4] = fmaf(acc[4], dinv, blo(xv.z)); h[5] = fmaf(acc[5], dinv, bhi(xv.z));
        h[6] = fmaf(acc[6], dinv, blo(xv.w)); h[7] = fmaf(acc[7], dinv, bhi(xv.w));
#pragma unroll
        for (int t = 0; t < 8; ++t) h[t] = lrelu(h[t]);
        uint4 pk;
        pk.x = pack2(h[0], h[1]); pk.y = pack2(h[2], h[3]);
        pk.z = pack2(h[4], h[5]); pk.w = pack2(h[6], h[7]);
        *reinterpret_cast<uint4*>(&hsh[nll][li * 8]) = pk;
        // rows with n >= N stay uninitialized; their MFMA outputs are guarded.
    }
    __syncthreads();                                // lsrc dead -> out-stage
    // ---- gemm2: hsh[128][64] bf16 @ Wb2, stage hl fp8 + hr bf16 in LDS ----
    unsigned char* hl_st = reinterpret_cast<unsigned char*>(lsrc);       // 4 KB
    ushort16* hr_st = reinterpret_cast<ushort16*>(lsrc + 1024);          // 8 KB
    const int m0  = wid * 16;
    const int mlo = lane & 15;
    const int qk  = lane >> 4;
    frag Af[2];
#pragma unroll
    for (int kc = 0; kc < 2; ++kc)
        Af[kc] = *reinterpret_cast<const frag*>(&hsh[m0 + mlo][kc * 32 + qk * 8]);
#pragma unroll
    for (int ct = 0; ct < 4; ++ct) {
        f32x4 acc = {0.f, 0.f, 0.f, 0.f};
#pragma unroll
        for (int kc = 0; kc < 2; ++kc) {
            frag Bf = *reinterpret_cast<const frag*>(
                &Wb2[(ct * 16 + mlo) * 64 + kc * 32 + qk * 8]);
            acc = __builtin_amdgcn_mfma_f32_16x16x32_bf16(Af[kc], Bf, acc, 0, 0, 0);
        }
        const int col = ct * 16 + mlo;
#pragma unroll
        for (int r = 0; r < 4; ++r) {
            int row = m0 + qk * 4 + r;
            if (col < OUT_DIM) hl_st[row * 32 + col] = f2fp8(acc[r]);
            else hr_st[row * 32 + (col - OUT_DIM)] = f2b(acc[r] + b2[col - OUT_DIM]);
        }
    }
    __syncthreads();
    // coalesced bulk stores: hl 128x2 uint4, hr 128x4 uint4
    for (int idx = tid; idx < 128 * 2; idx += 512) {
        int row = idx >> 1, ch = idx & 1;
        int node = n0 + (half << 7) + row;
        if (node < N)
            reinterpret_cast<uint4*>(hl8)[(long)node * 2 + ch] =
                reinterpret_cast<const uint4*>(hl_st)[idx];
    }
    for (int idx = tid; idx < 128 * 4; idx += 512) {
        int row = idx >> 2, ch = idx & 3;
        int node = n0 + (half << 7) + row;
        if (node < N)
            reinterpret_cast<uint4*>(hr)[(long)node * 4 + ch] =
                reinterpret_cast<const uint4*>(hr_st)[idx];
    }
}

// ---- agg2: z = LR(mean-gather(hl fp8) + hr bf16) ----
// 4 lanes/node x 8B, 16 nodes/wave, 16 uint2 gathers in flight; hl total
// footprint 3.2 MB -> per-XCD-L2-resident.
__global__ __launch_bounds__(256) void agg2_final_kernel(
    const int* __restrict__ rowptr, const int* __restrict__ degA,
    const uint32* __restrict__ srcs,
    const uint2* __restrict__ hlq, const uint4* __restrict__ hrq,
    float* __restrict__ z, int N) {
    const int lane  = threadIdx.x & 63;
    const int li    = lane & 3;
    const int gbase = lane & 60;
    const int wave  = (blockIdx.x << 2) + (threadIdx.x >> 6);
    const int n     = wave * 16 + (lane >> 2);
    if (n >= N) return;
    const int rp = rowptr[n];
    const int d  = degA[n];
    float acc[8] = {};
    int j = 0;
    while (j + 16 <= d) {
        int sA = (int)srcs[rp + j + li];
        int sB = (int)srcs[rp + j + 4 + li];
        int sC = (int)srcs[rp + j + 8 + li];
        int sD = (int)srcs[rp + j + 12 + li];
        uint2 u[16];
#pragma unroll
        for (int t = 0; t < 4; ++t) u[t]      = hlq[(long)__shfl(sA, gbase + t) * 4 + li];
#pragma unroll
        for (int t = 0; t < 4; ++t) u[4 + t]  = hlq[(long)__shfl(sB, gbase + t) * 4 + li];
#pragma unroll
        for (int t = 0; t < 4; ++t) u[8 + t]  = hlq[(long)__shfl(sC, gbase + t) * 4 + li];
#pragma unroll
        for (int t = 0; t < 4; ++t) u[12 + t] = hlq[(long)__shfl(sD, gbase + t) * 4 + li];
#pragma unroll
        for (int t = 0; t < 16; ++t) addq8(acc, u[t]);
        j += 16;
    }
    while (j + 4 <= d) {
        int sA = (int)srcs[rp + j + li];
        uint2 u[4];
#pragma unroll
        for (int t = 0; t < 4; ++t) u[t] = hlq[(long)__shfl(sA, gbase + t) * 4 + li];
#pragma unroll
        for (int t = 0; t < 4; ++t) addq8(acc, u[t]);
        j += 4;
    }
    int r = d - j;                     // 0..3
    if (r > 0) {
        int sA = (int)srcs[rp + j + ((li < r) ? li : 0)];
#pragma unroll
        for (int t = 0; t < 3; ++t) {
            if (t < r) {
                uint2 u = hlq[(long)__shfl(sA, gbase + t) * 4 + li];
                addq8(acc, u);
            }
        }
    }
    const float dinv = (d > 0) ? (1.f / (float)d) : 1.f;
    uint4 hv = hrq[(long)n * 4 + li];               // 8 bf16 hr values
    float4 vA, vB;
    vA.x = lrelu(fmaf(acc[0], dinv, blo(hv.x))); vA.y = lrelu(fmaf(acc[1], dinv, bhi(hv.x)));
    vA.z = lrelu(fmaf(acc[2], dinv, blo(hv.y))); vA.w = lrelu(fmaf(acc[3], dinv, bhi(hv.y)));
    vB.x = lrelu(fmaf(acc[4], dinv, blo(hv.z))); vB.y = lrelu(fmaf(acc[5], dinv, bhi(hv.z)));
    vB.z = lrelu(fmaf(acc[6], dinv, blo(hv.w))); vB.w = lrelu(fmaf(acc[7], dinv, bhi(hv.w)));
    *reinterpret_cast<float4*>(&z[(long)n * OUT_DIM + 8 * li]) = vA;
    *reinterpret_cast<float4*>(&z[(long)n * OUT_DIM + 8 * li + 4]) = vB;
}

extern "C" void kernel_launch(void* const* d_in, const int* in_sizes, int n_in,
                              void* d_out, int out_size, void* d_ws, size_t ws_size,
                              hipStream_t stream) {
    const float* x   = (const float*)d_in[0];
    const int*   ei  = (const int*)d_in[1];
    const float* Wl1 = (const float*)d_in[2];
    const float* Wr1 = (const float*)d_in[3];
    const float* b1  = (const float*)d_in[4];
    const float* Wl2 = (const float*)d_in[5];
    const float* Wr2 = (const float*)d_in[6];
    const float* b2  = (const float*)d_in[7];

    const int N = in_sizes[0] / IN_DIM;
    const int E = in_sizes[1] / 2;
    const int* src = ei;
    const int* dst = ei + E;
    const int NB = (N + 255) >> NPB_SHIFT;   // buckets (<= 512)

    char* p = (char*)d_ws;
    int* bhist    = (int*)p;           p += sizeof(int) * NBMAX;
    int* done     = (int*)p;           p += sizeof(int) * 4;
    int* pbase    = (int*)p;           p += sizeof(int) * NBMAX;
    int* bcur     = (int*)p;           p += sizeof(int) * NBMAX;
    int* rowptr   = (int*)p;           p += sizeof(int) * (N + 4);
    int* degA     = (int*)p;           p += sizeof(int) * (N + 4);
    uint32* pairs = (uint32*)p;        p += sizeof(uint32) * ((size_t)E + 16 * NBMAX);
    uint32* srcs  = (uint32*)p;        p += sizeof(uint32) * ((size_t)E + 16 * NBMAX);
    ushort16* Wb1 = (ushort16*)p;      p += sizeof(ushort16) * 128 * 128;
    ushort16* Wb2 = (ushort16*)p;      p += sizeof(ushort16) * 64 * 64;
    uchar8* xl8   = (uchar8*)p;        p += sizeof(uchar8) * ((size_t)N * HID + 64);
    ushort16* xr  = (ushort16*)p;      p += sizeof(ushort16) * ((size_t)N * HID + 8);
    uchar8* hl8   = (uchar8*)p;        p += sizeof(uchar8) * ((size_t)N * OUT_DIM + 64);
    ushort16* hr  = (ushort16*)p;      p += sizeof(ushort16) * ((size_t)N * OUT_DIM + 8);

    const int ngemm = (N + 63) / 64;
    const int npart = (E + CHUNK - 1) / CHUNK;
    prep_kernel<<<32, 256, 0, stream>>>(Wl1, Wr1, Wl2, Wr2, Wb1, Wb2, bhist, done);
    hist_scan_kernel<<<256, 256, 0, stream>>>(dst, bhist, pbase, bcur, done, E, NB);
    gemm1_part_kernel<<<npart + ngemm, 256, 0, stream>>>(
        x, Wb1, b1, src, dst, bcur, pairs, xl8, xr, N, E, NB, npart);
    agg1_gemm2_kernel<<<NB * 2, 512, 0, stream>>>(pairs, bhist, pbase,
                                                  (const uint2*)xl8, (const uint4*)xr,
                                                  Wb2, b2,
                                                  srcs, rowptr, degA, hl8, hr, N);
    agg2_final_kernel<<<(N + 63) / 64, 256, 0, stream>>>(rowptr, degA, srcs,
                                                         (const uint2*)hl8,
                                                         (const uint4*)hr,
                                                         (float*)d_out, N);
}

// Round 13
// 244.359 us; speedup vs baseline: 1.0225x; 1.0225x over previous
//
#include <hip/hip_runtime.h>

// SAGEConv x2 forward. Edges bucket-partitioned by dst (256 nodes/bucket).
// Pipeline (5 dispatches, no host-side memset — graph-capture safe):
//   prep        : zero bhist/done, convert weights to bf16
//   hist_scan   : bucket histogram + (last block) padded prefix scan
//   gemm1_part  : MFMA gemm1 + partition in ONE grid; partition uses
//                 perm[]+buck[] (O(1) flush, no binary search) and
//                 per-block-rotated gbase atomics (desynchronized)
//   agg1_gemm2  : LDS sort + fp8 gather-mean (R0 loop shape, uint2/lane) +
//                 h in LDS + MFMA gemm2 -> hl fp8 / hr bf16 (LDS-staged)
//   agg2_final  : gather-mean over hl fp8 (3.2 MB, per-XCD-L2-resident) + epi
// Lessons encoded: in-block LDS sort beats global-CSR precompute (R10);
// ALL scattered stores go LDS->coalesced uint4 (R8/R9); fp8 tables halve
// gather bytes at unchanged request count (R11); synchronized global-atomic
// storms serialize per-address — stagger them per block (R13).

constexpr int IN_DIM  = 128;
constexpr int HID     = 64;
constexpr int OUT_DIM = 32;
constexpr float SLOPE = 0.1f;
constexpr int NPB_SHIFT = 8;     // 256 nodes per bucket
constexpr int NBMAX = 512;       // max buckets (N <= 131072)
constexpr int CHUNK = 4096;      // edges per partition block
constexpr int SUBCAP = 4096;     // per-half-bucket edge capacity (avg ~2048)

typedef unsigned int uint32;
typedef unsigned short ushort16;
typedef unsigned char uchar8;
using floatx2 = __attribute__((ext_vector_type(2))) float;

__device__ inline float blo(uint32 u) { return __uint_as_float(u << 16); }
__device__ inline float bhi(uint32 u) { return __uint_as_float(u & 0xffff0000u); }
__device__ inline ushort16 f2b(float f) {
    uint32 u = __float_as_uint(f);
    u += 0x7fffu + ((u >> 16) & 1u);   // round-to-nearest-even
    return (ushort16)(u >> 16);
}
__device__ inline uint32 pack2(float lo, float hi) {
    return (uint32)f2b(lo) | ((uint32)f2b(hi) << 16);
}
__device__ inline float lrelu(float v) { return (v > 0.f) ? v : SLOPE * v; }
__device__ inline uchar8 f2fp8(float f) {                // e4m3, RNE (HW)
    uint32 r = (uint32)__builtin_amdgcn_cvt_pk_fp8_f32(f, f, 0, false);
    return (uchar8)(r & 0xffu);
}
__device__ inline void addp4(float* acc, uint32 w) {     // fp8 x4 decode+add
    floatx2 a = __builtin_amdgcn_cvt_pk_f32_fp8((int)w, false);
    floatx2 b = __builtin_amdgcn_cvt_pk_f32_fp8((int)w, true);
    acc[0] += a[0]; acc[1] += a[1]; acc[2] += b[0]; acc[3] += b[1];
}
__device__ inline void addq8(float* acc, uint2 u) {      // fp8 x8
    addp4(acc + 0, u.x); addp4(acc + 4, u.y);
}

// ---- prep: zero bhist/done + convert weights to bf16 [col][k] layouts ----
__global__ __launch_bounds__(256) void prep_kernel(
    const float* __restrict__ Wl1, const float* __restrict__ Wr1,
    const float* __restrict__ Wl2, const float* __restrict__ Wr2,
    ushort16* __restrict__ Wb1, ushort16* __restrict__ Wb2,
    int* __restrict__ bhist, int* __restrict__ done) {
    const int gid = blockIdx.x * 256 + threadIdx.x;
    if (gid < NBMAX) bhist[gid] = 0;
    if (gid == NBMAX) *done = 0;
    for (int i = gid; i < 128 * 128; i += gridDim.x * 256) {
        int c = i >> 7, k = i & 127;
        Wb1[i] = f2b((c < HID) ? Wl1[k * HID + c] : Wr1[k * HID + (c - HID)]);
    }
    for (int i = gid; i < 64 * 64; i += gridDim.x * 256) {
        int c = i >> 6, k = i & 63;
        Wb2[i] = f2b((c < OUT_DIM) ? Wl2[k * OUT_DIM + c]
                                   : Wr2[k * OUT_DIM + (c - OUT_DIM)]);
    }
}

// ---- bucket histogram + fused scan (last-finishing block) ----
__global__ __launch_bounds__(256) void hist_scan_kernel(
    const int* __restrict__ dst, int* __restrict__ bhist,
    int* __restrict__ pbase, int* __restrict__ bcur,
    int* __restrict__ done, int E, int NB) {
    __shared__ int bh[NBMAX];
    __shared__ int s2[256];
    __shared__ int flag;
    const int tid = threadIdx.x;
    for (int i = tid; i < NBMAX; i += 256) bh[i] = 0;
    __syncthreads();
    for (int e = blockIdx.x * 256 + tid; e < E; e += gridDim.x * 256)
        atomicAdd(&bh[dst[e] >> NPB_SHIFT], 1);
    __syncthreads();
    for (int b = tid; b < NBMAX; b += 256)
        if (bh[b]) atomicAdd(&bhist[b], bh[b]);
    __threadfence();
    if (tid == 0) flag = (atomicAdd(done, 1) == (int)gridDim.x - 1) ? 1 : 0;
    __syncthreads();
    if (!flag) return;
    // last block: exclusive scan of 16-padded bucket sizes (512 bins, 256 thr)
    __threadfence();
    int v0 = atomicAdd(&bhist[2 * tid], 0);       // coherent-point read
    int v1 = atomicAdd(&bhist[2 * tid + 1], 0);
    int p0 = (v0 + 15) & ~15, p1 = (v1 + 15) & ~15;
    s2[tid] = p0 + p1; __syncthreads();
    for (int off = 1; off < 256; off <<= 1) {
        int b = (tid >= off) ? s2[tid - off] : 0;
        __syncthreads();
        s2[tid] += b;
        __syncthreads();
    }
    int base = s2[tid] - (p0 + p1);
    pbase[2 * tid]     = base;      bcur[2 * tid]     = base;
    pbase[2 * tid + 1] = base + p0; bcur[2 * tid + 1] = base + p0;
}

// ---- fused: partition blocks (blockIdx < npart) + MFMA gemm1 blocks ----
// partition: edges -> bucket regions of pairs[]; scatter records perm+buck,
// flush is O(1) per edge (no binary search) and re-reads src/dst (L2-hot);
// gbase atomics rotated by blockIdx to desynchronize per-address contention.
// gemm1: x[N,128] @ Wb1 -> xl fp8[N,64], xr bf16[N,64]+b1 (LDS-staged
// coalesced stores). A-tile-only LDS.
__global__ __launch_bounds__(256) void gemm1_part_kernel(
    const float* __restrict__ x, const ushort16* __restrict__ Wb1,
    const float* __restrict__ b1,
    const int* __restrict__ src, const int* __restrict__ dst,
    int* __restrict__ bcur, uint32* __restrict__ pairs,
    uchar8* __restrict__ xl8, ushort16* __restrict__ xr,
    int N, int E, int NB, int npart) {
    using frag = __attribute__((ext_vector_type(8))) short;
    using f32x4 = __attribute__((ext_vector_type(4))) float;
    constexpr int LDA = IN_DIM + 8;                 // 136 elems = 272 B
    __shared__ union {
        struct {
            int hist[NBMAX], loff[NBMAX], cur[NBMAX], gbase[NBMAX];
            int s[256];
            ushort16 perm[CHUNK];                   // 8 KB local edge index
            ushort16 buck[CHUNK];                   // 8 KB bucket of position
        } p;                                        // 25 KB
        ushort16 Ash[64][LDA];                      // 17.4 KB
        struct { uchar8 xl[64][64]; ushort16 xr[64][64]; } o;  // 12 KB stage
    } sm;
    const int tid = threadIdx.x;
    if (blockIdx.x < npart) {                       // ---- partition path ----
        const int e0  = blockIdx.x * CHUNK;
        const int cnt = min(CHUNK, E - e0);
        for (int i = tid; i < NBMAX; i += 256) sm.p.hist[i] = 0;
        __syncthreads();
        int dreg[16];
#pragma unroll
        for (int k = 0; k < 16; ++k) {
            int i = tid + k * 256;
            if (i < cnt) {
                dreg[k] = dst[e0 + i];
                atomicAdd(&sm.p.hist[dreg[k] >> NPB_SHIFT], 1);
            }
        }
        __syncthreads();
        int a0 = sm.p.hist[2 * tid], a1 = sm.p.hist[2 * tid + 1];
        sm.p.s[tid] = a0 + a1; __syncthreads();
        for (int off = 1; off < 256; off <<= 1) {
            int t = (tid >= off) ? sm.p.s[tid - off] : 0;
            __syncthreads();
            sm.p.s[tid] += t;
            __syncthreads();
        }
        int ex = sm.p.s[tid] - (a0 + a1);
        sm.p.loff[2 * tid] = ex;      sm.p.loff[2 * tid + 1] = ex + a0;
        sm.p.cur[2 * tid]  = ex;      sm.p.cur[2 * tid + 1]  = ex + a0;
        __syncthreads();
#pragma unroll
        for (int k = 0; k < 16; ++k) {              // scatter perm + bucket
            int i = tid + k * 256;
            if (i < cnt) {
                int b = dreg[k] >> NPB_SHIFT;
                int pos = atomicAdd(&sm.p.cur[b], 1);
                sm.p.perm[pos] = (ushort16)i;
                sm.p.buck[pos] = (ushort16)b;
            }
        }
        __syncthreads();
        // gbase atomics, rotated start per block to desynchronize contention
        for (int bb = tid; bb < NB; bb += 256) {
            int b = bb + (int)blockIdx.x;
            if (b >= NB) b -= NB;
            if (b >= NB) b -= NB;                   // blockIdx < npart ~ NB
            int cb = sm.p.hist[b];
            if (cb) sm.p.gbase[b] = atomicAdd(&bcur[b], cb);
        }
        __syncthreads();
        for (int i = tid; i < cnt; i += 256) {      // O(1) flush via buck[]
            int pidx = sm.p.perm[i];
            int b    = sm.p.buck[i];
            int sv = src[e0 + pidx];                // L2-resident (just read)
            int dv = dst[e0 + pidx];
            pairs[sm.p.gbase[b] + (i - sm.p.loff[b])] =
                (uint32)sv | ((uint32)(dv & 255) << 24);
        }
        return;
    }
    // ---- gemm1 path ----
    const int n0 = (blockIdx.x - npart) * 64;
    {
        const int lc = (tid & 31) * 4;
        for (int row = tid >> 5; row < 64; row += 8) {
            int node = n0 + row;
            float4 xv = (node < N)
                ? *reinterpret_cast<const float4*>(&x[(long)node * IN_DIM + lc])
                : float4{0.f, 0.f, 0.f, 0.f};
            ushort16 pk[4] = {f2b(xv.x), f2b(xv.y), f2b(xv.z), f2b(xv.w)};
            *reinterpret_cast<ushort2*>(&sm.Ash[row][lc])     = ushort2{pk[0], pk[1]};
            *reinterpret_cast<ushort2*>(&sm.Ash[row][lc + 2]) = ushort2{pk[2], pk[3]};
        }
    }
    __syncthreads();
    const int lane = tid & 63;
    const int m0   = (tid >> 6) * 16;
    const int mlo  = lane & 15;
    const int qk   = lane >> 4;
    frag Af[4];
#pragma unroll
    for (int kc = 0; kc < 4; ++kc)
        Af[kc] = *reinterpret_cast<const frag*>(&sm.Ash[m0 + mlo][kc * 32 + qk * 8]);
    __syncthreads();                                // Ash dead -> o reuse
#pragma unroll
    for (int ct = 0; ct < 8; ++ct) {
        f32x4 acc = {0.f, 0.f, 0.f, 0.f};
#pragma unroll
        for (int kc = 0; kc < 4; ++kc) {
            frag Bf = *reinterpret_cast<const frag*>(
                &Wb1[(ct * 16 + mlo) * 128 + kc * 32 + qk * 8]);
            acc = __builtin_amdgcn_mfma_f32_16x16x32_bf16(Af[kc], Bf, acc, 0, 0, 0);
        }
        const int col = ct * 16 + mlo;
#pragma unroll
        for (int r = 0; r < 4; ++r) {
            int row = m0 + qk * 4 + r;
            if (col < HID) sm.o.xl[row][col] = f2fp8(acc[r]);
            else           sm.o.xr[row][col - HID] = f2b(acc[r] + b1[col - HID]);
        }
    }
    __syncthreads();
    // coalesced bulk stores: xl 64x4 uint4, xr 64x8 uint4
    for (int idx = tid; idx < 64 * 4; idx += 256) {
        int row = idx >> 2, ch = idx & 3;
        int node = n0 + row;
        if (node < N)
            reinterpret_cast<uint4*>(xl8)[(long)node * 4 + ch] =
                reinterpret_cast<const uint4*>(&sm.o.xl[0][0])[idx];
    }
    for (int idx = tid; idx < 64 * 8; idx += 256) {
        int row = idx >> 3, ch = idx & 7;
        int node = n0 + row;
        if (node < N)
            reinterpret_cast<uint4*>(xr)[(long)node * 8 + ch] =
                reinterpret_cast<const uint4*>(&sm.o.xr[0][0])[idx];
    }
}

// ---- agg1 + fine-bin + gemm2 fused: block = half-bucket (128 nodes) ----
// Sorts the bucket's pairs in LDS, emits CSR (srcs/rowptr/deg) for agg2,
// computes h = LR(mean-gather(xl fp8) + xr bf16) into an LDS bf16 tile
// (R0 loop shape: 8 lanes/node x uint2, 2 passes, 16/8/tail), then the
// 128x64 @ 64x64 MFMA gemm2 -> hl fp8 / hr bf16 staged in LDS, coalesced.
__global__ __launch_bounds__(512) void agg1_gemm2_kernel(
    const uint32* __restrict__ pairs, const int* __restrict__ bhist,
    const int* __restrict__ pbase,
    const uint2* __restrict__ xlq, const uint4* __restrict__ xrq,
    const ushort16* __restrict__ Wb2, const float* __restrict__ b2,
    uint32* __restrict__ srcs, int* __restrict__ rowptr, int* __restrict__ degA,
    uchar8* __restrict__ hl8, ushort16* __restrict__ hr, int N) {
    using frag = __attribute__((ext_vector_type(8))) short;
    using f32x4 = __attribute__((ext_vector_type(4))) float;
    constexpr int LDH = HID + 8;                    // 72 elems = 144 B
    __shared__ int hist[256], loff[256], cur[128];
    __shared__ int lsrc[SUBCAP];                    // 16 KB (reused as out-stage)
    __shared__ ushort16 hsh[128][LDH];              // 18 KB bf16 h-tile
    const int tid  = threadIdx.x;
    const int bkt  = blockIdx.x >> 1;
    const int half = blockIdx.x & 1;
    const int n0   = bkt << NPB_SHIFT;
    const int base = pbase[bkt];
    const int sz   = bhist[bkt];
    if (tid < 256) hist[tid] = 0;
    __syncthreads();
    for (int i = tid; i < sz; i += 512)
        atomicAdd(&hist[pairs[base + i] >> 24], 1);
    __syncthreads();
    int v = (tid < 256) ? hist[tid] : 0;
    if (tid < 256) loff[tid] = v;
    __syncthreads();
    for (int off = 1; off < 256; off <<= 1) {
        int t = (tid >= off && tid < 256) ? loff[tid - off] : 0;
        __syncthreads();
        if (tid < 256) loff[tid] += t;
        __syncthreads();
    }
    if (tid < 256) loff[tid] -= v;                  // exclusive
    __syncthreads();
    if (half == 0 && tid < 256 && n0 + tid < N) {   // CSR for agg2
        rowptr[n0 + tid] = base + loff[tid];
        degA[n0 + tid]   = hist[tid];
    }
    const int hbase = loff[half << 7];
    const int hcnt  = (half ? sz : loff[128]) - hbase;
    if (tid < 128) cur[tid] = loff[(half << 7) + tid] - hbase;
    __syncthreads();
    for (int i = tid; i < sz; i += 512) {           // scatter my half into lsrc
        uint32 u = pairs[base + i];
        int dl = u >> 24;
        if ((dl >> 7) == half) {
            int pos = atomicAdd(&cur[dl & 127], 1);
            lsrc[pos] = (int)(u & 0xFFFFFFu);
        }
    }
    __syncthreads();
    for (int i = tid; i < hcnt; i += 512)           // coalesced CSR srcs
        srcs[base + hbase + i] = (uint32)lsrc[i];
    // ---- gather: 8 lanes/node x uint2 fp8, 8 nodes/wave, 2 passes ----
    const int lane = tid & 63;
    const int wid  = tid >> 6;
    const int li   = lane & 7;
#pragma unroll
    for (int pass = 0; pass < 2; ++pass) {
        const int nll = pass * 64 + wid * 8 + (lane >> 3);  // row in hsh 0..127
        const int nl  = (half << 7) + nll;
        const int n   = n0 + nl;
        if (n >= N) continue;
        const int lo0 = loff[nl] - hbase;
        const int d   = hist[nl];
        float acc[8] = {};
        int j = 0;
        while (j + 16 <= d) {
            int i0[8], i1[8];
#pragma unroll
            for (int t = 0; t < 8; ++t) i0[t] = lsrc[lo0 + j + t];
#pragma unroll
            for (int t = 0; t < 8; ++t) i1[t] = lsrc[lo0 + j + 8 + t];
            uint2 u0[8], u1[8];
#pragma unroll
            for (int t = 0; t < 8; ++t) u0[t] = xlq[(long)i0[t] * 8 + li];
#pragma unroll
            for (int t = 0; t < 8; ++t) u1[t] = xlq[(long)i1[t] * 8 + li];
#pragma unroll
            for (int t = 0; t < 8; ++t) { addq8(acc, u0[t]); addq8(acc, u1[t]); }
            j += 16;
        }
        if (j + 8 <= d) {
            int i0[8];
#pragma unroll
            for (int t = 0; t < 8; ++t) i0[t] = lsrc[lo0 + j + t];
            uint2 u0[8];
#pragma unroll
            for (int t = 0; t < 8; ++t) u0[t] = xlq[(long)i0[t] * 8 + li];
#pragma unroll
            for (int t = 0; t < 8; ++t) addq8(acc, u0[t]);
            j += 8;
        }
        for (; j < d; ++j) {
            uint2 u = xlq[(long)lsrc[lo0 + j] * 8 + li];
            addq8(acc, u);
        }
        const float dinv = (d > 0) ? (1.f / (float)d) : 1.f;
        uint4 xv = xrq[(long)n * 8 + li];           // 8 bf16 xr values
        float h[8];
        h[0] = fmaf(acc[0], dinv, blo(xv.x)); h[1] = fmaf(acc[1], dinv, bhi(xv.x));
        h[2] = fmaf(acc[2], dinv, blo(xv.y)); h[3] = fmaf(acc[3], dinv, bhi(xv.y));
        h[4] = fmaf(acc[4], dinv, blo(xv.z)); h[5] = fmaf(acc[5], dinv, bhi(xv.z));
        h[6] = fmaf(acc[6], dinv, blo(xv.w)); h[7] = fmaf(acc[7], dinv, bhi(xv.w));
#pragma unroll
        for (int t = 0; t < 8; ++t) h[t] = lrelu(h[t]);
        uint4 pk;
        pk.x = pack2(h[0], h[1]); pk.y = pack2(h[2], h[3]);
        pk.z = pack2(h[4], h[5]); pk.w = pack2(h[6], h[7]);
        *reinterpret_cast<uint4*>(&hsh[nll][li * 8]) = pk;
        // rows with n >= N stay uninitialized; their MFMA outputs are guarded.
    }
    __syncthreads();                                // lsrc dead -> out-stage
    // ---- gemm2: hsh[128][64] bf16 @ Wb2, stage hl fp8 + hr bf16 in LDS ----
    unsigned char* hl_st = reinterpret_cast<unsigned char*>(lsrc);       // 4 KB
    ushort16* hr_st = reinterpret_cast<ushort16*>(lsrc + 1024);          // 8 KB
    const int m0  = wid * 16;
    const int mlo = lane & 15;
    const int qk  = lane >> 4;
    frag Af[2];
#pragma unroll
    for (int kc = 0; kc < 2; ++kc)
        Af[kc] = *reinterpret_cast<const frag*>(&hsh[m0 + mlo][kc * 32 + qk * 8]);
#pragma unroll
    for (int ct = 0; ct < 4; ++ct) {
        f32x4 acc = {0.f, 0.f, 0.f, 0.f};
#pragma unroll
        for (int kc = 0; kc < 2; ++kc) {
            frag Bf = *reinterpret_cast<const frag*>(
                &Wb2[(ct * 16 + mlo) * 64 + kc * 32 + qk * 8]);
            acc = __builtin_amdgcn_mfma_f32_16x16x32_bf16(Af[kc], Bf, acc, 0, 0, 0);
        }
        const int col = ct * 16 + mlo;
#pragma unroll
        for (int r = 0; r < 4; ++r) {
            int row = m0 + qk * 4 + r;
            if (col < OUT_DIM) hl_st[row * 32 + col] = f2fp8(acc[r]);
            else hr_st[row * 32 + (col - OUT_DIM)] = f2b(acc[r] + b2[col - OUT_DIM]);
        }
    }
    __syncthreads();
    // coalesced bulk stores: hl 128x2 uint4, hr 128x4 uint4
    for (int idx = tid; idx < 128 * 2; idx += 512) {
        int row = idx >> 1, ch = idx & 1;
        int node = n0 + (half << 7) + row;
        if (node < N)
            reinterpret_cast<uint4*>(hl8)[(long)node * 2 + ch] =
                reinterpret_cast<const uint4*>(hl_st)[idx];
    }
    for (int idx = tid; idx < 128 * 4; idx += 512) {
        int row = idx >> 2, ch = idx & 3;
        int node = n0 + (half << 7) + row;
        if (node < N)
            reinterpret_cast<uint4*>(hr)[(long)node * 4 + ch] =
                reinterpret_cast<const uint4*>(hr_st)[idx];
    }
}

// ---- agg2: z = LR(mean-gather(hl fp8) + hr bf16) ----
// 4 lanes/node x 8B, 16 nodes/wave, 16 uint2 gathers in flight; hl total
// footprint 3.2 MB -> per-XCD-L2-resident.
__global__ __launch_bounds__(256) void agg2_final_kernel(
    const int* __restrict__ rowptr, const int* __restrict__ degA,
    const uint32* __restrict__ srcs,
    const uint2* __restrict__ hlq, const uint4* __restrict__ hrq,
    float* __restrict__ z, int N) {
    const int lane  = threadIdx.x & 63;
    const int li    = lane & 3;
    const int gbase = lane & 60;
    const int wave  = (blockIdx.x << 2) + (threadIdx.x >> 6);
    const int n     = wave * 16 + (lane >> 2);
    if (n >= N) return;
    const int rp = rowptr[n];
    const int d  = degA[n];
    float acc[8] = {};
    int j = 0;
    while (j + 16 <= d) {
        int sA = (int)srcs[rp + j + li];
        int sB = (int)srcs[rp + j + 4 + li];
        int sC = (int)srcs[rp + j + 8 + li];
        int sD = (int)srcs[rp + j + 12 + li];
        uint2 u[16];
#pragma unroll
        for (int t = 0; t < 4; ++t) u[t]      = hlq[(long)__shfl(sA, gbase + t) * 4 + li];
#pragma unroll
        for (int t = 0; t < 4; ++t) u[4 + t]  = hlq[(long)__shfl(sB, gbase + t) * 4 + li];
#pragma unroll
        for (int t = 0; t < 4; ++t) u[8 + t]  = hlq[(long)__shfl(sC, gbase + t) * 4 + li];
#pragma unroll
        for (int t = 0; t < 4; ++t) u[12 + t] = hlq[(long)__shfl(sD, gbase + t) * 4 + li];
#pragma unroll
        for (int t = 0; t < 16; ++t) addq8(acc, u[t]);
        j += 16;
    }
    while (j + 4 <= d) {
        int sA = (int)srcs[rp + j + li];
        uint2 u[4];
#pragma unroll
        for (int t = 0; t < 4; ++t) u[t] = hlq[(long)__shfl(sA, gbase + t) * 4 + li];
#pragma unroll
        for (int t = 0; t < 4; ++t) addq8(acc, u[t]);
        j += 4;
    }
    int r = d - j;                     // 0..3
    if (r > 0) {
        int sA = (int)srcs[rp + j + ((li < r) ? li : 0)];
#pragma unroll
        for (int t = 0; t < 3; ++t) {
            if (t < r) {
                uint2 u = hlq[(long)__shfl(sA, gbase + t) * 4 + li];
                addq8(acc, u);
            }
        }
    }
    const float dinv = (d > 0) ? (1.f / (float)d) : 1.f;
    uint4 hv = hrq[(long)n * 4 + li];               // 8 bf16 hr values
    float4 vA, vB;
    vA.x = lrelu(fmaf(acc[0], dinv, blo(hv.x))); vA.y = lrelu(fmaf(acc[1], dinv, bhi(hv.x)));
    vA.z = lrelu(fmaf(acc[2], dinv, blo(hv.y))); vA.w = lrelu(fmaf(acc[3], dinv, bhi(hv.y)));
    vB.x = lrelu(fmaf(acc[4], dinv, blo(hv.z))); vB.y = lrelu(fmaf(acc[5], dinv, bhi(hv.z)));
    vB.z = lrelu(fmaf(acc[6], dinv, blo(hv.w))); vB.w = lrelu(fmaf(acc[7], dinv, bhi(hv.w)));
    *reinterpret_cast<float4*>(&z[(long)n * OUT_DIM + 8 * li]) = vA;
    *reinterpret_cast<float4*>(&z[(long)n * OUT_DIM + 8 * li + 4]) = vB;
}

extern "C" void kernel_launch(void* const* d_in, const int* in_sizes, int n_in,
                              void* d_out, int out_size, void* d_ws, size_t ws_size,
                              hipStream_t stream) {
    const float* x   = (const float*)d_in[0];
    const int*   ei  = (const int*)d_in[1];
    const float* Wl1 = (const float*)d_in[2];
    const float* Wr1 = (const float*)d_in[3];
    const float* b1  = (const float*)d_in[4];
    const float* Wl2 = (const float*)d_in[5];
    const float* Wr2 = (const float*)d_in[6];
    const float* b2  = (const float*)d_in[7];

    const int N = in_sizes[0] / IN_DIM;
    const int E = in_sizes[1] / 2;
    const int* src = ei;
    const int* dst = ei + E;
    const int NB = (N + 255) >> NPB_SHIFT;   // buckets (<= 512)

    char* p = (char*)d_ws;
    int* bhist    = (int*)p;           p += sizeof(int) * NBMAX;
    int* done     = (int*)p;           p += sizeof(int) * 4;
    int* pbase    = (int*)p;           p += sizeof(int) * NBMAX;
    int* bcur     = (int*)p;           p += sizeof(int) * NBMAX;
    int* rowptr   = (int*)p;           p += sizeof(int) * (N + 4);
    int* degA     = (int*)p;           p += sizeof(int) * (N + 4);
    uint32* pairs = (uint32*)p;        p += sizeof(uint32) * ((size_t)E + 16 * NBMAX);
    uint32* srcs  = (uint32*)p;        p += sizeof(uint32) * ((size_t)E + 16 * NBMAX);
    ushort16* Wb1 = (ushort16*)p;      p += sizeof(ushort16) * 128 * 128;
    ushort16* Wb2 = (ushort16*)p;      p += sizeof(ushort16) * 64 * 64;
    uchar8* xl8   = (uchar8*)p;        p += sizeof(uchar8) * ((size_t)N * HID + 64);
    ushort16* xr  = (ushort16*)p;      p += sizeof(ushort16) * ((size_t)N * HID + 8);
    uchar8* hl8   = (uchar8*)p;        p += sizeof(uchar8) * ((size_t)N * OUT_DIM + 64);
    ushort16* hr  = (ushort16*)p;      p += sizeof(ushort16) * ((size_t)N * OUT_DIM + 8);

    const int ngemm = (N + 63) / 64;
    const int npart = (E + CHUNK - 1) / CHUNK;
    prep_kernel<<<32, 256, 0, stream>>>(Wl1, Wr1, Wl2, Wr2, Wb1, Wb2, bhist, done);
    hist_scan_kernel<<<256, 256, 0, stream>>>(dst, bhist, pbase, bcur, done, E, NB);
    gemm1_part_kernel<<<npart + ngemm, 256, 0, stream>>>(
        x, Wb1, b1, src, dst, bcur, pairs, xl8, xr, N, E, NB, npart);
    agg1_gemm2_kernel<<<NB * 2, 512, 0, stream>>>(pairs, bhist, pbase,
                                                  (const uint2*)xl8, (const uint4*)xr,
                                                  Wb2, b2,
                                                  srcs, rowptr, degA, hl8, hr, N);
    agg2_final_kernel<<<(N + 63) / 64, 256, 0, stream>>>(rowptr, degA, srcs,
                                                         (const uint2*)hl8,
                                                         (const uint4*)hr,
                                                         (float*)d_out, N);
}

// Round 14
// 238.161 us; speedup vs baseline: 1.0492x; 1.0260x over previous
//
#include <hip/hip_runtime.h>

// SAGEConv x2 forward. Edges bucket-partitioned by dst (256 nodes/bucket).
// Pipeline (6 dispatches, no host-side memset — graph-capture safe):
//   prep        : zero bhist/done, convert weights to bf16
//   hist_scan   : bucket histogram + (last block) padded prefix scan
//   gemm1_part  : MFMA gemm1 + partition in ONE grid (perm+buck O(1) flush,
//                 rotated gbase atomics); xl fp8 / xr bf16 LDS-staged stores
//   sort        : per-half-bucket LDS fine-sort -> srcs/rowptr/degA (CSR)
//   gather_gemm2: 64 nodes/block (256 thr, ~8 blocks/CU): stage contiguous
//                 srcs run -> LDS, fp8 gather-mean (R0 loop), h in LDS,
//                 MFMA gemm2 -> hl fp8 / hr bf16 (LDS-staged stores)
//   agg2_final  : gather-mean over hl fp8 (3.2 MB, L2-resident) + epilogue
// Lessons: in-block LDS sort beats global-CSR atomics (R10); scattered
// stores go LDS->coalesced (R9); fp8 tables halve gather bytes (R11/R13);
// sort-at-bucket-granularity must not cap the gather's occupancy (R14).

constexpr int IN_DIM  = 128;
constexpr int HID     = 64;
constexpr int OUT_DIM = 32;
constexpr float SLOPE = 0.1f;
constexpr int NPB_SHIFT = 8;     // 256 nodes per bucket
constexpr int NBMAX = 512;       // max buckets (N <= 131072)
constexpr int CHUNK = 4096;      // edges per partition block
constexpr int SUBCAP = 4096;     // per-half-bucket edge capacity (avg ~2048)
constexpr int GCAP  = 2048;      // per-64-node gather capacity (avg ~1024)

typedef unsigned int uint32;
typedef unsigned short ushort16;
typedef unsigned char uchar8;
using floatx2 = __attribute__((ext_vector_type(2))) float;

__device__ inline float blo(uint32 u) { return __uint_as_float(u << 16); }
__device__ inline float bhi(uint32 u) { return __uint_as_float(u & 0xffff0000u); }
__device__ inline ushort16 f2b(float f) {
    uint32 u = __float_as_uint(f);
    u += 0x7fffu + ((u >> 16) & 1u);   // round-to-nearest-even
    return (ushort16)(u >> 16);
}
__device__ inline uint32 pack2(float lo, float hi) {
    return (uint32)f2b(lo) | ((uint32)f2b(hi) << 16);
}
__device__ inline float lrelu(float v) { return (v > 0.f) ? v : SLOPE * v; }
__device__ inline uchar8 f2fp8(float f) {                // e4m3, RNE (HW)
    uint32 r = (uint32)__builtin_amdgcn_cvt_pk_fp8_f32(f, f, 0, false);
    return (uchar8)(r & 0xffu);
}
__device__ inline void addp4(float* acc, uint32 w) {     // fp8 x4 decode+add
    floatx2 a = __builtin_amdgcn_cvt_pk_f32_fp8((int)w, false);
    floatx2 b = __builtin_amdgcn_cvt_pk_f32_fp8((int)w, true);
    acc[0] += a[0]; acc[1] += a[1]; acc[2] += b[0]; acc[3] += b[1];
}
__device__ inline void addq8(float* acc, uint2 u) {      // fp8 x8
    addp4(acc + 0, u.x); addp4(acc + 4, u.y);
}

// ---- prep: zero bhist/done + convert weights to bf16 [col][k] layouts ----
__global__ __launch_bounds__(256) void prep_kernel(
    const float* __restrict__ Wl1, const float* __restrict__ Wr1,
    const float* __restrict__ Wl2, const float* __restrict__ Wr2,
    ushort16* __restrict__ Wb1, ushort16* __restrict__ Wb2,
    int* __restrict__ bhist, int* __restrict__ done) {
    const int gid = blockIdx.x * 256 + threadIdx.x;
    if (gid < NBMAX) bhist[gid] = 0;
    if (gid == NBMAX) *done = 0;
    for (int i = gid; i < 128 * 128; i += gridDim.x * 256) {
        int c = i >> 7, k = i & 127;
        Wb1[i] = f2b((c < HID) ? Wl1[k * HID + c] : Wr1[k * HID + (c - HID)]);
    }
    for (int i = gid; i < 64 * 64; i += gridDim.x * 256) {
        int c = i >> 6, k = i & 63;
        Wb2[i] = f2b((c < OUT_DIM) ? Wl2[k * OUT_DIM + c]
                                   : Wr2[k * OUT_DIM + (c - OUT_DIM)]);
    }
}

// ---- bucket histogram + fused scan (last-finishing block) ----
__global__ __launch_bounds__(256) void hist_scan_kernel(
    const int* __restrict__ dst, int* __restrict__ bhist,
    int* __restrict__ pbase, int* __restrict__ bcur,
    int* __restrict__ done, int E, int NB) {
    __shared__ int bh[NBMAX];
    __shared__ int s2[256];
    __shared__ int flag;
    const int tid = threadIdx.x;
    for (int i = tid; i < NBMAX; i += 256) bh[i] = 0;
    __syncthreads();
    for (int e = blockIdx.x * 256 + tid; e < E; e += gridDim.x * 256)
        atomicAdd(&bh[dst[e] >> NPB_SHIFT], 1);
    __syncthreads();
    for (int b = tid; b < NBMAX; b += 256)
        if (bh[b]) atomicAdd(&bhist[b], bh[b]);
    __threadfence();
    if (tid == 0) flag = (atomicAdd(done, 1) == (int)gridDim.x - 1) ? 1 : 0;
    __syncthreads();
    if (!flag) return;
    // last block: exclusive scan of 16-padded bucket sizes (512 bins, 256 thr)
    __threadfence();
    int v0 = atomicAdd(&bhist[2 * tid], 0);       // coherent-point read
    int v1 = atomicAdd(&bhist[2 * tid + 1], 0);
    int p0 = (v0 + 15) & ~15, p1 = (v1 + 15) & ~15;
    s2[tid] = p0 + p1; __syncthreads();
    for (int off = 1; off < 256; off <<= 1) {
        int b = (tid >= off) ? s2[tid - off] : 0;
        __syncthreads();
        s2[tid] += b;
        __syncthreads();
    }
    int base = s2[tid] - (p0 + p1);
    pbase[2 * tid]     = base;      bcur[2 * tid]     = base;
    pbase[2 * tid + 1] = base + p0; bcur[2 * tid + 1] = base + p0;
}

// ---- fused: partition blocks (blockIdx < npart) + MFMA gemm1 blocks ----
__global__ __launch_bounds__(256) void gemm1_part_kernel(
    const float* __restrict__ x, const ushort16* __restrict__ Wb1,
    const float* __restrict__ b1,
    const int* __restrict__ src, const int* __restrict__ dst,
    int* __restrict__ bcur, uint32* __restrict__ pairs,
    uchar8* __restrict__ xl8, ushort16* __restrict__ xr,
    int N, int E, int NB, int npart) {
    using frag = __attribute__((ext_vector_type(8))) short;
    using f32x4 = __attribute__((ext_vector_type(4))) float;
    constexpr int LDA = IN_DIM + 8;                 // 136 elems = 272 B
    __shared__ union {
        struct {
            int hist[NBMAX], loff[NBMAX], cur[NBMAX], gbase[NBMAX];
            int s[256];
            ushort16 perm[CHUNK];                   // 8 KB local edge index
            ushort16 buck[CHUNK];                   // 8 KB bucket of position
        } p;                                        // 25 KB
        ushort16 Ash[64][LDA];                      // 17.4 KB
        struct { uchar8 xl[64][64]; ushort16 xr[64][64]; } o;  // 12 KB stage
    } sm;
    const int tid = threadIdx.x;
    if (blockIdx.x < npart) {                       // ---- partition path ----
        const int e0  = blockIdx.x * CHUNK;
        const int cnt = min(CHUNK, E - e0);
        for (int i = tid; i < NBMAX; i += 256) sm.p.hist[i] = 0;
        __syncthreads();
        int dreg[16];
#pragma unroll
        for (int k = 0; k < 16; ++k) {
            int i = tid + k * 256;
            if (i < cnt) {
                dreg[k] = dst[e0 + i];
                atomicAdd(&sm.p.hist[dreg[k] >> NPB_SHIFT], 1);
            }
        }
        __syncthreads();
        int a0 = sm.p.hist[2 * tid], a1 = sm.p.hist[2 * tid + 1];
        sm.p.s[tid] = a0 + a1; __syncthreads();
        for (int off = 1; off < 256; off <<= 1) {
            int t = (tid >= off) ? sm.p.s[tid - off] : 0;
            __syncthreads();
            sm.p.s[tid] += t;
            __syncthreads();
        }
        int ex = sm.p.s[tid] - (a0 + a1);
        sm.p.loff[2 * tid] = ex;      sm.p.loff[2 * tid + 1] = ex + a0;
        sm.p.cur[2 * tid]  = ex;      sm.p.cur[2 * tid + 1]  = ex + a0;
        __syncthreads();
#pragma unroll
        for (int k = 0; k < 16; ++k) {              // scatter perm + bucket
            int i = tid + k * 256;
            if (i < cnt) {
                int b = dreg[k] >> NPB_SHIFT;
                int pos = atomicAdd(&sm.p.cur[b], 1);
                sm.p.perm[pos] = (ushort16)i;
                sm.p.buck[pos] = (ushort16)b;
            }
        }
        __syncthreads();
        // gbase atomics, rotated start per block to desynchronize contention
        for (int bb = tid; bb < NB; bb += 256) {
            int b = bb + (int)blockIdx.x;
            if (b >= NB) b -= NB;
            if (b >= NB) b -= NB;
            int cb = sm.p.hist[b];
            if (cb) sm.p.gbase[b] = atomicAdd(&bcur[b], cb);
        }
        __syncthreads();
        for (int i = tid; i < cnt; i += 256) {      // O(1) flush via buck[]
            int pidx = sm.p.perm[i];
            int b    = sm.p.buck[i];
            int sv = src[e0 + pidx];                // L2-resident (just read)
            int dv = dst[e0 + pidx];
            pairs[sm.p.gbase[b] + (i - sm.p.loff[b])] =
                (uint32)sv | ((uint32)(dv & 255) << 24);
        }
        return;
    }
    // ---- gemm1 path ----
    const int n0 = (blockIdx.x - npart) * 64;
    {
        const int lc = (tid & 31) * 4;
        for (int row = tid >> 5; row < 64; row += 8) {
            int node = n0 + row;
            float4 xv = (node < N)
                ? *reinterpret_cast<const float4*>(&x[(long)node * IN_DIM + lc])
                : float4{0.f, 0.f, 0.f, 0.f};
            ushort16 pk[4] = {f2b(xv.x), f2b(xv.y), f2b(xv.z), f2b(xv.w)};
            *reinterpret_cast<ushort2*>(&sm.Ash[row][lc])     = ushort2{pk[0], pk[1]};
            *reinterpret_cast<ushort2*>(&sm.Ash[row][lc + 2]) = ushort2{pk[2], pk[3]};
        }
    }
    __syncthreads();
    const int lane = tid & 63;
    const int m0   = (tid >> 6) * 16;
    const int mlo  = lane & 15;
    const int qk   = lane >> 4;
    frag Af[4];
#pragma unroll
    for (int kc = 0; kc < 4; ++kc)
        Af[kc] = *reinterpret_cast<const frag*>(&sm.Ash[m0 + mlo][kc * 32 + qk * 8]);
    __syncthreads();                                // Ash dead -> o reuse
#pragma unroll
    for (int ct = 0; ct < 8; ++ct) {
        f32x4 acc = {0.f, 0.f, 0.f, 0.f};
#pragma unroll
        for (int kc = 0; kc < 4; ++kc) {
            frag Bf = *reinterpret_cast<const frag*>(
                &Wb1[(ct * 16 + mlo) * 128 + kc * 32 + qk * 8]);
            acc = __builtin_amdgcn_mfma_f32_16x16x32_bf16(Af[kc], Bf, acc, 0, 0, 0);
        }
        const int col = ct * 16 + mlo;
#pragma unroll
        for (int r = 0; r < 4; ++r) {
            int row = m0 + qk * 4 + r;
            if (col < HID) sm.o.xl[row][col] = f2fp8(acc[r]);
            else           sm.o.xr[row][col - HID] = f2b(acc[r] + b1[col - HID]);
        }
    }
    __syncthreads();
    // coalesced bulk stores: xl 64x4 uint4, xr 64x8 uint4
    for (int idx = tid; idx < 64 * 4; idx += 256) {
        int row = idx >> 2, ch = idx & 3;
        int node = n0 + row;
        if (node < N)
            reinterpret_cast<uint4*>(xl8)[(long)node * 4 + ch] =
                reinterpret_cast<const uint4*>(&sm.o.xl[0][0])[idx];
    }
    for (int idx = tid; idx < 64 * 8; idx += 256) {
        int row = idx >> 3, ch = idx & 7;
        int node = n0 + row;
        if (node < N)
            reinterpret_cast<uint4*>(xr)[(long)node * 8 + ch] =
                reinterpret_cast<const uint4*>(&sm.o.xr[0][0])[idx];
    }
}

// ---- sort: block = half-bucket (128 nodes). LDS fine-sort of the bucket's
// pairs -> coalesced srcs (CSR order) + rowptr/degA. (= old agg1 prologue.)
__global__ __launch_bounds__(512) void sort_kernel(
    const uint32* __restrict__ pairs, const int* __restrict__ bhist,
    const int* __restrict__ pbase,
    uint32* __restrict__ srcs, int* __restrict__ rowptr, int* __restrict__ degA,
    int N) {
    __shared__ int hist[256], loff[256], cur[128];
    __shared__ int lsrc[SUBCAP];                    // 16 KB
    const int tid  = threadIdx.x;
    const int bkt  = blockIdx.x >> 1;
    const int half = blockIdx.x & 1;
    const int n0   = bkt << NPB_SHIFT;
    const int base = pbase[bkt];
    const int sz   = bhist[bkt];
    if (tid < 256) hist[tid] = 0;
    __syncthreads();
    for (int i = tid; i < sz; i += 512)
        atomicAdd(&hist[pairs[base + i] >> 24], 1);
    __syncthreads();
    int v = (tid < 256) ? hist[tid] : 0;
    if (tid < 256) loff[tid] = v;
    __syncthreads();
    for (int off = 1; off < 256; off <<= 1) {
        int t = (tid >= off && tid < 256) ? loff[tid - off] : 0;
        __syncthreads();
        if (tid < 256) loff[tid] += t;
        __syncthreads();
    }
    if (tid < 256) loff[tid] -= v;                  // exclusive
    __syncthreads();
    if (half == 0 && tid < 256 && n0 + tid < N) {   // CSR for gather+agg2
        rowptr[n0 + tid] = base + loff[tid];
        degA[n0 + tid]   = hist[tid];
    }
    const int hbase = loff[half << 7];
    const int hcnt  = (half ? sz : loff[128]) - hbase;
    if (tid < 128) cur[tid] = loff[(half << 7) + tid] - hbase;
    __syncthreads();
    for (int i = tid; i < sz; i += 512) {           // scatter my half into lsrc
        uint32 u = pairs[base + i];
        int dl = u >> 24;
        if ((dl >> 7) == half) {
            int pos = atomicAdd(&cur[dl & 127], 1);
            lsrc[pos] = (int)(u & 0xFFFFFFu);
        }
    }
    __syncthreads();
    for (int i = tid; i < hcnt; i += 512)           // coalesced CSR srcs
        srcs[base + hbase + i] = (uint32)lsrc[i];
}

// ---- gather + gemm2: block = 64 consecutive nodes, 256 threads ----
// Stage the block's contiguous srcs run into LDS (coalesced), fp8
// gather-mean (R0 loop shape: 8 lanes/node x uint2, 2 passes of 32 nodes),
// h -> LDS bf16 tile, MFMA gemm2 64x64 -> hl fp8 / hr bf16 (LDS-staged).
// LDS ~18 KB -> 8 blocks/CU (thread-capped), 2x the fused version's waves.
__global__ __launch_bounds__(256) void gather_gemm2_kernel(
    const uint32* __restrict__ srcs, const int* __restrict__ rowptr,
    const int* __restrict__ degA,
    const uint2* __restrict__ xlq, const uint4* __restrict__ xrq,
    const ushort16* __restrict__ Wb2, const float* __restrict__ b2,
    uchar8* __restrict__ hl8, ushort16* __restrict__ hr, int N) {
    using frag = __attribute__((ext_vector_type(8))) short;
    using f32x4 = __attribute__((ext_vector_type(4))) float;
    constexpr int LDH = HID + 8;                    // 72 elems = 144 B
    __shared__ int rps[64], dgs[64];
    __shared__ int lsrc[GCAP];                      // 8 KB (reused as out-stage)
    __shared__ ushort16 hsh[64][LDH];               // 9.2 KB bf16 h-tile
    const int tid = threadIdx.x;
    const int n0  = blockIdx.x * 64;
    if (tid < 64) {
        int nn = n0 + tid;
        rps[tid] = (nn < N) ? rowptr[nn] : 0;
        dgs[tid] = (nn < N) ? degA[nn] : 0;
    }
    __syncthreads();
    const int nvalid = min(64, N - n0);             // >=1 (grid sized by N)
    const int rp0 = rps[0];
    int sz = rps[nvalid - 1] + dgs[nvalid - 1] - rp0;
    if (sz > GCAP) sz = GCAP;                       // 32-sigma safe (mean 1024)
    for (int i = tid; i < sz; i += 256)             // coalesced stage
        lsrc[i] = (int)srcs[rp0 + i];
    __syncthreads();
    // ---- gather: 8 lanes/node x uint2 fp8, 8 nodes/wave, 2 passes ----
    const int lane = tid & 63;
    const int wid  = tid >> 6;                      // 0..3
    const int li   = lane & 7;
#pragma unroll
    for (int pass = 0; pass < 2; ++pass) {
        const int nl = pass * 32 + wid * 8 + (lane >> 3);   // 0..63
        const int n  = n0 + nl;
        if (n >= N) continue;
        const int lo0 = rps[nl] - rp0;
        const int d   = dgs[nl];
        float acc[8] = {};
        int j = 0;
        while (j + 16 <= d) {
            int i0[8], i1[8];
#pragma unroll
            for (int t = 0; t < 8; ++t) i0[t] = lsrc[lo0 + j + t];
#pragma unroll
            for (int t = 0; t < 8; ++t) i1[t] = lsrc[lo0 + j + 8 + t];
            uint2 u0[8], u1[8];
#pragma unroll
            for (int t = 0; t < 8; ++t) u0[t] = xlq[(long)i0[t] * 8 + li];
#pragma unroll
            for (int t = 0; t < 8; ++t) u1[t] = xlq[(long)i1[t] * 8 + li];
#pragma unroll
            for (int t = 0; t < 8; ++t) { addq8(acc, u0[t]); addq8(acc, u1[t]); }
            j += 16;
        }
        if (j + 8 <= d) {
            int i0[8];
#pragma unroll
            for (int t = 0; t < 8; ++t) i0[t] = lsrc[lo0 + j + t];
            uint2 u0[8];
#pragma unroll
            for (int t = 0; t < 8; ++t) u0[t] = xlq[(long)i0[t] * 8 + li];
#pragma unroll
            for (int t = 0; t < 8; ++t) addq8(acc, u0[t]);
            j += 8;
        }
        for (; j < d; ++j) {
            uint2 u = xlq[(long)lsrc[lo0 + j] * 8 + li];
            addq8(acc, u);
        }
        const float dinv = (d > 0) ? (1.f / (float)d) : 1.f;
        uint4 xv = xrq[(long)n * 8 + li];           // 8 bf16 xr values
        float h[8];
        h[0] = fmaf(acc[0], dinv, blo(xv.x)); h[1] = fmaf(acc[1], dinv, bhi(xv.x));
        h[2] = fmaf(acc[2], dinv, blo(xv.y)); h[3] = fmaf(acc[3], dinv, bhi(xv.y));
        h[4] = fmaf(acc[4], dinv, blo(xv.z)); h[5] = fmaf(acc[5], dinv, bhi(xv.z));
        h[6] = fmaf(acc[6], dinv, blo(xv.w)); h[7] = fmaf(acc[7], dinv, bhi(xv.w));
#pragma unroll
        for (int t = 0; t < 8; ++t) h[t] = lrelu(h[t]);
        uint4 pk;
        pk.x = pack2(h[0], h[1]); pk.y = pack2(h[2], h[3]);
        pk.z = pack2(h[4], h[5]); pk.w = pack2(h[6], h[7]);
        *reinterpret_cast<uint4*>(&hsh[nl][li * 8]) = pk;
        // rows with n >= N stay uninitialized; their MFMA outputs are guarded.
    }
    __syncthreads();                                // lsrc dead -> out-stage
    // ---- gemm2: hsh[64][64] bf16 @ Wb2, stage hl fp8 + hr bf16 in LDS ----
    unsigned char* hl_st = reinterpret_cast<unsigned char*>(lsrc);       // 2 KB
    ushort16* hr_st = reinterpret_cast<ushort16*>(lsrc + 512);           // 4 KB
    const int m0  = wid * 16;
    const int mlo = lane & 15;
    const int qk  = lane >> 4;
    frag Af[2];
#pragma unroll
    for (int kc = 0; kc < 2; ++kc)
        Af[kc] = *reinterpret_cast<const frag*>(&hsh[m0 + mlo][kc * 32 + qk * 8]);
#pragma unroll
    for (int ct = 0; ct < 4; ++ct) {
        f32x4 acc = {0.f, 0.f, 0.f, 0.f};
#pragma unroll
        for (int kc = 0; kc < 2; ++kc) {
            frag Bf = *reinterpret_cast<const frag*>(
                &Wb2[(ct * 16 + mlo) * 64 + kc * 32 + qk * 8]);
            acc = __builtin_amdgcn_mfma_f32_16x16x32_bf16(Af[kc], Bf, acc, 0, 0, 0);
        }
        const int col = ct * 16 + mlo;
#pragma unroll
        for (int r = 0; r < 4; ++r) {
            int row = m0 + qk * 4 + r;
            if (col < OUT_DIM) hl_st[row * 32 + col] = f2fp8(acc[r]);
            else hr_st[row * 32 + (col - OUT_DIM)] = f2b(acc[r] + b2[col - OUT_DIM]);
        }
    }
    __syncthreads();
    // coalesced bulk stores: hl 64x2 uint4, hr 64x4 uint4
    for (int idx = tid; idx < 64 * 2; idx += 256) {
        int row = idx >> 1, ch = idx & 1;
        int node = n0 + row;
        if (node < N)
            reinterpret_cast<uint4*>(hl8)[(long)node * 2 + ch] =
                reinterpret_cast<const uint4*>(hl_st)[idx];
    }
    for (int idx = tid; idx < 64 * 4; idx += 256) {
        int row = idx >> 2, ch = idx & 3;
        int node = n0 + row;
        if (node < N)
            reinterpret_cast<uint4*>(hr)[(long)node * 4 + ch] =
                reinterpret_cast<const uint4*>(hr_st)[idx];
    }
}

// ---- agg2: z = LR(mean-gather(hl fp8) + hr bf16) ----
// 4 lanes/node x 8B, 16 nodes/wave, 16 uint2 gathers in flight; hl total
// footprint 3.2 MB -> per-XCD-L2-resident.
__global__ __launch_bounds__(256) void agg2_final_kernel(
    const int* __restrict__ rowptr, const int* __restrict__ degA,
    const uint32* __restrict__ srcs,
    const uint2* __restrict__ hlq, const uint4* __restrict__ hrq,
    float* __restrict__ z, int N) {
    const int lane  = threadIdx.x & 63;
    const int li    = lane & 3;
    const int gbase = lane & 60;
    const int wave  = (blockIdx.x << 2) + (threadIdx.x >> 6);
    const int n     = wave * 16 + (lane >> 2);
    if (n >= N) return;
    const int rp = rowptr[n];
    const int d  = degA[n];
    float acc[8] = {};
    int j = 0;
    while (j + 16 <= d) {
        int sA = (int)srcs[rp + j + li];
        int sB = (int)srcs[rp + j + 4 + li];
        int sC = (int)srcs[rp + j + 8 + li];
        int sD = (int)srcs[rp + j + 12 + li];
        uint2 u[16];
#pragma unroll
        for (int t = 0; t < 4; ++t) u[t]      = hlq[(long)__shfl(sA, gbase + t) * 4 + li];
#pragma unroll
        for (int t = 0; t < 4; ++t) u[4 + t]  = hlq[(long)__shfl(sB, gbase + t) * 4 + li];
#pragma unroll
        for (int t = 0; t < 4; ++t) u[8 + t]  = hlq[(long)__shfl(sC, gbase + t) * 4 + li];
#pragma unroll
        for (int t = 0; t < 4; ++t) u[12 + t] = hlq[(long)__shfl(sD, gbase + t) * 4 + li];
#pragma unroll
        for (int t = 0; t < 16; ++t) addq8(acc, u[t]);
        j += 16;
    }
    while (j + 4 <= d) {
        int sA = (int)srcs[rp + j + li];
        uint2 u[4];
#pragma unroll
        for (int t = 0; t < 4; ++t) u[t] = hlq[(long)__shfl(sA, gbase + t) * 4 + li];
#pragma unroll
        for (int t = 0; t < 4; ++t) addq8(acc, u[t]);
        j += 4;
    }
    int r = d - j;                     // 0..3
    if (r > 0) {
        int sA = (int)srcs[rp + j + ((li < r) ? li : 0)];
#pragma unroll
        for (int t = 0; t < 3; ++t) {
            if (t < r) {
                uint2 u = hlq[(long)__shfl(sA, gbase + t) * 4 + li];
                addq8(acc, u);
            }
        }
    }
    const float dinv = (d > 0) ? (1.f / (float)d) : 1.f;
    uint4 hv = hrq[(long)n * 4 + li];               // 8 bf16 hr values
    float4 vA, vB;
    vA.x = lrelu(fmaf(acc[0], dinv, blo(hv.x))); vA.y = lrelu(fmaf(acc[1], dinv, bhi(hv.x)));
    vA.z = lrelu(fmaf(acc[2], dinv, blo(hv.y))); vA.w = lrelu(fmaf(acc[3], dinv, bhi(hv.y)));
    vB.x = lrelu(fmaf(acc[4], dinv, blo(hv.z))); vB.y = lrelu(fmaf(acc[5], dinv, bhi(hv.z)));
    vB.z = lrelu(fmaf(acc[6], dinv, blo(hv.w))); vB.w = lrelu(fmaf(acc[7], dinv, bhi(hv.w)));
    *reinterpret_cast<float4*>(&z[(long)n * OUT_DIM + 8 * li]) = vA;
    *reinterpret_cast<float4*>(&z[(long)n * OUT_DIM + 8 * li + 4]) = vB;
}

extern "C" void kernel_launch(void* const* d_in, const int* in_sizes, int n_in,
                              void* d_out, int out_size, void* d_ws, size_t ws_size,
                              hipStream_t stream) {
    const float* x   = (const float*)d_in[0];
    const int*   ei  = (const int*)d_in[1];
    const float* Wl1 = (const float*)d_in[2];
    const float* Wr1 = (const float*)d_in[3];
    const float* b1  = (const float*)d_in[4];
    const float* Wl2 = (const float*)d_in[5];
    const float* Wr2 = (const float*)d_in[6];
    const float* b2  = (const float*)d_in[7];

    const int N = in_sizes[0] / IN_DIM;
    const int E = in_sizes[1] / 2;
    const int* src = ei;
    const int* dst = ei + E;
    const int NB = (N + 255) >> NPB_SHIFT;   // buckets (<= 512)

    char* p = (char*)d_ws;
    int* bhist    = (int*)p;           p += sizeof(int) * NBMAX;
    int* done     = (int*)p;           p += sizeof(int) * 4;
    int* pbase    = (int*)p;           p += sizeof(int) * NBMAX;
    int* bcur     = (int*)p;           p += sizeof(int) * NBMAX;
    int* rowptr   = (int*)p;           p += sizeof(int) * (N + 4);
    int* degA     = (int*)p;           p += sizeof(int) * (N + 4);
    uint32* pairs = (uint32*)p;        p += sizeof(uint32) * ((size_t)E + 16 * NBMAX);
    uint32* srcs  = (uint32*)p;        p += sizeof(uint32) * ((size_t)E + 16 * NBMAX);
    ushort16* Wb1 = (ushort16*)p;      p += sizeof(ushort16) * 128 * 128;
    ushort16* Wb2 = (ushort16*)p;      p += sizeof(ushort16) * 64 * 64;
    uchar8* xl8   = (uchar8*)p;        p += sizeof(uchar8) * ((size_t)N * HID + 64);
    ushort16* xr  = (ushort16*)p;      p += sizeof(ushort16) * ((size_t)N * HID + 8);
    uchar8* hl8   = (uchar8*)p;        p += sizeof(uchar8) * ((size_t)N * OUT_DIM + 64);
    ushort16* hr  = (ushort16*)p;      p += sizeof(ushort16) * ((size_t)N * OUT_DIM + 8);

    const int ngemm = (N + 63) / 64;
    const int npart = (E + CHUNK - 1) / CHUNK;
    prep_kernel<<<32, 256, 0, stream>>>(Wl1, Wr1, Wl2, Wr2, Wb1, Wb2, bhist, done);
    hist_scan_kernel<<<256, 256, 0, stream>>>(dst, bhist, pbase, bcur, done, E, NB);
    gemm1_part_kernel<<<npart + ngemm, 256, 0, stream>>>(
        x, Wb1, b1, src, dst, bcur, pairs, xl8, xr, N, E, NB, npart);
    sort_kernel<<<NB * 2, 512, 0, stream>>>(pairs, bhist, pbase,
                                            srcs, rowptr, degA, N);
    gather_gemm2_kernel<<<(N + 63) / 64, 256, 0, stream>>>(
        srcs, rowptr, degA, (const uint2*)xl8, (const uint4*)xr,
        Wb2, b2, hl8, hr, N);
    agg2_final_kernel<<<(N + 63) / 64, 256, 0, stream>>>(rowptr, degA, srcs,
                                                         (const uint2*)hl8,
                                                         (const uint4*)hr,
                                                         (float*)d_out, N);
}